// Round 5
// baseline (321.268 us; speedup 1.0000x reference)
//
#include <hip/hip_runtime.h>
#include <hip/hip_bf16.h>

typedef __attribute__((ext_vector_type(8))) short bf16x8;
typedef __attribute__((ext_vector_type(4))) short bf16x4;
typedef __attribute__((ext_vector_type(4))) float f32x4;

#define DEVI static __device__ __forceinline__

constexpr int NAG = 32, DIN = 256, HDIM = 128, ADIM = 32;

// ws layout (bf16 element offsets). Frag order serves both A- and B-orientation:
//   elem ((ks*NM + mt)*64 + lane)*8 + j  <->  W[ks*32 + (lane>>4)*8 + j][mt*16 + (lane&15)]
constexpr int WS_ENC = 0;                  // 256x128
constexpr int WS_H   = 32768;              // 8 mats x 16384
constexpr int WS_QW  = 32768 + 8 * 16384;  // 128x32
constexpr int WS_TOT = WS_QW + 4096;

// strides (shorts). Row byte-size must be a 16B multiple for ds_read_b128.
constexpr int SH = 136;   // h/Q/K/attout rows [32][136]
constexpr int SV = 40;    // vT rows [128][40]
constexpr int SA = 40;    // AT rows [32][40]
constexpr int SX = 264;   // x staging [32][264]

// LDS: P0/P1/P2 = 8704 each, PV = 10240 -> 36352 B -> 4 blocks/CU
constexpr int L_P0 = 0;
constexpr int L_P1 = 8704;
constexpr int L_P2 = 17408;
constexpr int L_PV = 26112;
constexpr int L_TOT = 36352;

DEVI short f2bf(float f) {
  union { float f; unsigned u; } a; a.f = f;
  return (short)((a.u + 0x7fffu + ((a.u >> 16) & 1u)) >> 16);
}

// packed f32x2 -> bf16x2 (gfx950 V_CVT_PK_BF16_F32 when available; RNE both paths)
#if __has_builtin(__builtin_amdgcn_cvt_pk_bf16_f32)
typedef __attribute__((ext_vector_type(2))) __bf16 v2bf;
DEVI bf16x4 pk4(float x0, float x1, float x2, float x3) {
  union { v2bf v; unsigned u; } lo, hi;
  lo.v = __builtin_amdgcn_cvt_pk_bf16_f32(x0, x1);
  hi.v = __builtin_amdgcn_cvt_pk_bf16_f32(x2, x3);
  bf16x4 r;
  r[0] = (short)(lo.u & 0xffff); r[1] = (short)(lo.u >> 16);
  r[2] = (short)(hi.u & 0xffff); r[3] = (short)(hi.u >> 16);
  return r;
}
#else
DEVI bf16x4 pk4(float x0, float x1, float x2, float x3) {
  bf16x4 r;
  r[0] = f2bf(x0); r[1] = f2bf(x1); r[2] = f2bf(x2); r[3] = f2bf(x3);
  return r;
}
#endif

// ---------------- weight prep: coalesced float4 reads, scattered 2B writes ----
__global__ void prep_weights(const float* __restrict__ enc_w,
                             const float* __restrict__ m0, const float* __restrict__ m1,
                             const float* __restrict__ m2, const float* __restrict__ m3,
                             const float* __restrict__ m4, const float* __restrict__ m5,
                             const float* __restrict__ m6, const float* __restrict__ m7,
                             const float* __restrict__ qw,
                             short* __restrict__ ws)
{
  const int blk = blockIdx.x, tid = threadIdx.x;
  const float* src; int base, NM, nsh, f4;
  if (blk < 32) { src = enc_w; base = WS_ENC; NM = 8; nsh = 7; f4 = blk * 256 + tid; }
  else if (blk < 160) {
    const int m = (blk - 32) >> 4;
    if      (m == 0) src = m0; else if (m == 1) src = m1;
    else if (m == 2) src = m2; else if (m == 3) src = m3;
    else if (m == 4) src = m4; else if (m == 5) src = m5;
    else if (m == 6) src = m6; else             src = m7;
    base = WS_H + (m << 14); NM = 8; nsh = 7; f4 = ((blk - 32) & 15) * 256 + tid;
  } else { src = qw; base = WS_QW; NM = 2; nsh = 5; f4 = (blk - 160) * 256 + tid; }
  const int s = f4 * 4;
  const int row = s >> nsh, col0 = s & ((1 << nsh) - 1);
  const float4 v = *(const float4*)(src + s);
  const int j = row & 7, ks = row >> 5, lhi = ((row >> 3) & 3) * 16;
  const float vv[4] = {v.x, v.y, v.z, v.w};
#pragma unroll
  for (int c = 0; c < 4; ++c) {
    const int col = col0 + c;
    const int mt = col >> 4, lane = lhi + (col & 15);
    ws[base + (((ks * NM + mt) * 64 + lane) << 3) + j] = f2bf(vv[c]);
  }
}

// ---------------- swapped linear on 4 waves, distance-1 weight prefetch --------
// wave mg: m-tiles (features) mg*2+{0,1}; n-tiles (agents) {0,1}
template<int KSTEPS, bool RELU>
DEVI void linearSw4(const short* __restrict__ src, int sstride,
                    const short* __restrict__ wfrag, const float* __restrict__ bias,
                    short* __restrict__ dst,
                    int mg, int lr, int lq, int lane)
{
  f32x4 acc[2][2];
#pragma unroll
  for (int a = 0; a < 2; ++a)
#pragma unroll
    for (int b = 0; b < 2; ++b) acc[a][b] = (f32x4){0.f, 0.f, 0.f, 0.f};

  const bf16x8* wp = (const bf16x8*)wfrag;
  bf16x8 wc = wp[(mg * 2) * 64 + lane];
  bf16x8 hb[2];
#pragma unroll
  for (int step = 0; step < KSTEPS * 2; ++step) {
    const int ks = step >> 1, a = step & 1;
    bf16x8 wn;
    if (step + 1 < KSTEPS * 2) {
      const int s2 = step + 1;
      wn = wp[(((s2 >> 1) * 8) + mg * 2 + (s2 & 1)) * 64 + lane];
    }
    if (a == 0) {
#pragma unroll
      for (int b = 0; b < 2; ++b)
        hb[b] = *(const bf16x8*)(src + (b * 16 + lr) * sstride + ks * 32 + lq * 8);
    }
#pragma unroll
    for (int b = 0; b < 2; ++b)
      acc[a][b] = __builtin_amdgcn_mfma_f32_16x16x32_bf16(wc, hb[b], acc[a][b], 0, 0, 0);
    if (step + 1 < KSTEPS * 2) wc = wn;
  }
#pragma unroll
  for (int a = 0; a < 2; ++a) {
    const float4 bv = *(const float4*)(bias + (mg * 2 + a) * 16 + lq * 4);
#pragma unroll
    for (int b = 0; b < 2; ++b) {
      float v0 = acc[a][b][0] + bv.x, v1 = acc[a][b][1] + bv.y;
      float v2 = acc[a][b][2] + bv.z, v3 = acc[a][b][3] + bv.w;
      if (RELU) {
        v0 = fmaxf(v0, 0.f); v1 = fmaxf(v1, 0.f);
        v2 = fmaxf(v2, 0.f); v3 = fmaxf(v3, 0.f);
      }
      *(bf16x4*)(dst + (b * 16 + lr) * SH + (mg * 2 + a) * 16 + lq * 4) = pk4(v0, v1, v2, v3);
    }
  }
}

// ---------------- fused QKV with distance-1 (per ks,a step) weight prefetch ----
DEVI void qkv_pass4(const short* __restrict__ h,
                    const short* __restrict__ wq, const short* __restrict__ wk,
                    const short* __restrict__ wv,
                    const float* __restrict__ bq, const float* __restrict__ bk,
                    const float* __restrict__ bv,
                    short* __restrict__ Q, short* __restrict__ K, short* __restrict__ V,
                    int mg, int lr, int lq, int lane)
{
  f32x4 qa[2][2], ka[2][2], va[2][2];
#pragma unroll
  for (int a = 0; a < 2; ++a)
#pragma unroll
    for (int b = 0; b < 2; ++b) {
      qa[a][b] = (f32x4){0.f, 0.f, 0.f, 0.f};
      ka[a][b] = (f32x4){0.f, 0.f, 0.f, 0.f};
      va[a][b] = (f32x4){0.f, 0.f, 0.f, 0.f};
    }
  const bf16x8* wpq = (const bf16x8*)wq;
  const bf16x8* wpk = (const bf16x8*)wk;
  const bf16x8* wpv = (const bf16x8*)wv;
  const int i0 = (mg * 2) * 64 + lane;
  bf16x8 cq = wpq[i0], ck = wpk[i0], cv = wpv[i0];
  bf16x8 hf[2];
#pragma unroll
  for (int step = 0; step < 8; ++step) {
    const int ks = step >> 1, a = step & 1;
    bf16x8 nq, nk, nv;
    if (step < 7) {
      const int s2 = step + 1;
      const int idx = (((s2 >> 1) * 8) + mg * 2 + (s2 & 1)) * 64 + lane;
      nq = wpq[idx]; nk = wpk[idx]; nv = wpv[idx];
    }
    if (a == 0) {
#pragma unroll
      for (int b = 0; b < 2; ++b)
        hf[b] = *(const bf16x8*)(h + (b * 16 + lr) * SH + ks * 32 + lq * 8);
    }
#pragma unroll
    for (int b = 0; b < 2; ++b) {
      qa[a][b] = __builtin_amdgcn_mfma_f32_16x16x32_bf16(cq, hf[b], qa[a][b], 0, 0, 0);
      ka[a][b] = __builtin_amdgcn_mfma_f32_16x16x32_bf16(ck, hf[b], ka[a][b], 0, 0, 0);
      va[b][a] = __builtin_amdgcn_mfma_f32_16x16x32_bf16(hf[b], cv, va[b][a], 0, 0, 0);
    }
    if (step < 7) { cq = nq; ck = nk; cv = nv; }
  }
  // q, k epilogues: lane holds 4 consecutive features for fixed agent
#pragma unroll
  for (int a = 0; a < 2; ++a) {
    const float4 bq4 = *(const float4*)(bq + (mg * 2 + a) * 16 + lq * 4);
    const float4 bk4 = *(const float4*)(bk + (mg * 2 + a) * 16 + lq * 4);
#pragma unroll
    for (int b = 0; b < 2; ++b) {
      const int off = (b * 16 + lr) * SH + (mg * 2 + a) * 16 + lq * 4;
      *(bf16x4*)(Q + off) = pk4(fmaxf(qa[a][b][0] + bq4.x, 0.f), fmaxf(qa[a][b][1] + bq4.y, 0.f),
                                fmaxf(qa[a][b][2] + bq4.z, 0.f), fmaxf(qa[a][b][3] + bq4.w, 0.f));
      *(bf16x4*)(K + off) = pk4(fmaxf(ka[a][b][0] + bk4.x, 0.f), fmaxf(ka[a][b][1] + bk4.y, 0.f),
                                fmaxf(ka[a][b][2] + bk4.z, 0.f), fmaxf(ka[a][b][3] + bk4.w, 0.f));
    }
  }
  // v epilogue: normal orientation -> vT[feat][agent], 4 consecutive agents/lane
#pragma unroll
  for (int a = 0; a < 2; ++a) {
    const float bvv = bv[(mg * 2 + a) * 16 + lr];
#pragma unroll
    for (int b = 0; b < 2; ++b)
      *(bf16x4*)(V + ((mg * 2 + a) * 16 + lr) * SV + b * 16 + lq * 4) =
          pk4(fmaxf(va[b][a][0] + bvv, 0.f), fmaxf(va[b][a][1] + bvv, 0.f),
              fmaxf(va[b][a][2] + bvv, 0.f), fmaxf(va[b][a][3] + bvv, 0.f));
  }
}

// ---------------- scores + softmax on waves 0,1; mask pre-loaded in registers --
DEVI void scores_pass4(const short* __restrict__ Q, const short* __restrict__ K,
                       short* __restrict__ AT, const float4* __restrict__ mpre,
                       int qt, int lr, int lq)
{
  f32x4 sc[2];
  sc[0] = (f32x4){0.f, 0.f, 0.f, 0.f};
  sc[1] = (f32x4){0.f, 0.f, 0.f, 0.f};
#pragma unroll
  for (int ks = 0; ks < 4; ++ks) {
    const bf16x8 qf = *(const bf16x8*)(Q + (qt * 16 + lr) * SH + ks * 32 + lq * 8);
#pragma unroll
    for (int kt = 0; kt < 2; ++kt) {
      const bf16x8 kf = *(const bf16x8*)(K + (kt * 16 + lr) * SH + ks * 32 + lq * 8);
      sc[kt] = __builtin_amdgcn_mfma_f32_16x16x32_bf16(kf, qf, sc[kt], 0, 0, 0);
    }
  }
  // lane: q = qt*16+lr (fixed), k = kt*16 + lq*4 + r  (8 logits)
  float l[2][4];
  float M = -3.0e38f;
#pragma unroll
  for (int kt = 0; kt < 2; ++kt) {
    const float mm[4] = {mpre[kt].x, mpre[kt].y, mpre[kt].z, mpre[kt].w};
#pragma unroll
    for (int r = 0; r < 4; ++r) {
      const float v = sc[kt][r] * mm[r] - 9e15f * (1.f - mm[r]);
      l[kt][r] = v;
      M = fmaxf(M, v);
    }
  }
  M = fmaxf(M, __shfl_xor(M, 16));
  M = fmaxf(M, __shfl_xor(M, 32));
  float e[2][4], T = 0.f;
#pragma unroll
  for (int kt = 0; kt < 2; ++kt)
#pragma unroll
    for (int r = 0; r < 4; ++r) { e[kt][r] = __expf(l[kt][r] - M); T += e[kt][r]; }
  T += __shfl_xor(T, 16);
  T += __shfl_xor(T, 32);
  const float rT = __frcp_rn(T);
#pragma unroll
  for (int kt = 0; kt < 2; ++kt)
    *(bf16x4*)(AT + (qt * 16 + lr) * SA + kt * 16 + lq * 4) =
        pk4(e[kt][0] * rT, e[kt][1] * rT, e[kt][2] * rT, e[kt][3] * rT);
}

// ---------------- PV: attout[q][feat] = att @ v  (A=vT, B=AT) -------------------
DEVI void pv_pass4(const short* __restrict__ V, const short* __restrict__ AT,
                   short* __restrict__ AO, int wave, int lr, int lq)
{
  bf16x8 atf[2];
#pragma unroll
  for (int qt = 0; qt < 2; ++qt)
    atf[qt] = *(const bf16x8*)(AT + (qt * 16 + lr) * SA + lq * 8);
#pragma unroll
  for (int fi = 0; fi < 2; ++fi) {
    const int f2 = wave * 2 + fi;
    const bf16x8 vf = *(const bf16x8*)(V + (f2 * 16 + lr) * SV + lq * 8);
#pragma unroll
    for (int qt = 0; qt < 2; ++qt) {
      const f32x4 p = __builtin_amdgcn_mfma_f32_16x16x32_bf16(
          vf, atf[qt], (f32x4){0.f, 0.f, 0.f, 0.f}, 0, 0, 0);
      *(bf16x4*)(AO + (qt * 16 + lr) * SH + f2 * 16 + lq * 4) = pk4(p[0], p[1], p[2], p[3]);
    }
  }
}

DEVI void att_block4(const short* Rh, short* RQ, short* RK, short* RV,
                     short* RAT, short* RAO, short* Rout,
                     const short* wv, const short* wk, const short* wq, const short* wo,
                     const float* bv, const float* bk, const float* bq, const float* bo,
                     const float4* __restrict__ mpre,
                     int wave, int lr, int lq, int lane)
{
  qkv_pass4(Rh, wq, wk, wv, bq, bk, bv, RQ, RK, RV, wave, lr, lq, lane);
  __syncthreads();
  if (wave < 2) scores_pass4(RQ, RK, RAT, mpre, wave, lr, lq);
  __syncthreads();
  pv_pass4(RV, RAT, RAO, wave, lr, lq);
  __syncthreads();
  linearSw4<4, true>(RAO, SH, wo, bo, Rout, wave, lr, lq, lane);
  __syncthreads();
}

// ---------------- fused forward: one block (256 thr) = 1 batch element ---------
__global__ __launch_bounds__(256, 4)
void dgn_main(const float* __restrict__ x, const float* __restrict__ mask,
              const float* __restrict__ enc_b,
              const float* __restrict__ b1v, const float* __restrict__ b1k,
              const float* __restrict__ b1q, const float* __restrict__ b1o,
              const float* __restrict__ b2v, const float* __restrict__ b2k,
              const float* __restrict__ b2q, const float* __restrict__ b2o,
              const float* __restrict__ qb,
              const short* __restrict__ wf,
              float* __restrict__ out)
{
  __shared__ __align__(16) char smem[L_TOT];
  short* P0 = (short*)(smem + L_P0);
  short* P1 = (short*)(smem + L_P1);
  short* P2 = (short*)(smem + L_P2);
  short* PV = (short*)(smem + L_PV);
  short* XB = (short*)(smem + L_P1);   // x staging [32][264] = 16896 B over P1+P2

  const int tid = threadIdx.x;
  const int wave = tid >> 6, lane = tid & 63;
  const int lr = lane & 15, lq = lane >> 4;
  const int b0 = blockIdx.x;

  // preload mask for this batch element ONCE (same mask feeds both att blocks)
  float4 mpre[2];
  if (wave < 2) {
    const float* mp = mask + (size_t)b0 * (NAG * NAG) + (wave * 16 + lr) * 32;
    mpre[0] = *(const float4*)(mp + lq * 4);
    mpre[1] = *(const float4*)(mp + 16 + lq * 4);
  }

  // stage x (fp32 -> bf16)
  {
    const float4* xsrc = (const float4*)(x + (size_t)b0 * NAG * DIN);
#pragma unroll
    for (int it = 0; it < 8; ++it) {
      const int q4 = tid + it * 256;
      const float4 v = xsrc[q4];
      *(bf16x4*)(XB + (q4 >> 6) * SX + (q4 & 63) * 4) = pk4(v.x, v.y, v.z, v.w);
    }
  }
  __syncthreads();

  // encoder: h1[agent][feat] -> P0   (reads XB = P1+P2)
  linearSw4<8, true>(XB, SX, wf + WS_ENC, enc_b, P0, wave, lr, lq, lane);
  __syncthreads();

  // att1: h1=P0 -> Q=P1, K=P2, V=PV; AT=P0 (h1 dead); attout=P1 (Q dead); h2=P2 (K dead)
  att_block4(P0, P1, P2, PV, P0, P1, P2,
             wf + WS_H + 0 * 16384, wf + WS_H + 1 * 16384,
             wf + WS_H + 2 * 16384, wf + WS_H + 3 * 16384,
             b1v, b1k, b1q, b1o, mpre, wave, lr, lq, lane);

  // att2: h2=P2 -> Q=P0, K=P1, V=PV; AT=P2; attout=P0; h3=P1
  att_block4(P2, P0, P1, PV, P2, P0, P1,
             wf + WS_H + 4 * 16384, wf + WS_H + 5 * 16384,
             wf + WS_H + 6 * 16384, wf + WS_H + 7 * 16384,
             b2v, b2k, b2q, b2o, mpre, wave, lr, lq, lane);

  // head on waves 0,1: wave = agent-tile, both action-tiles -> full 128B lines
  if (wave < 2) {
    f32x4 ha[2];
    ha[0] = (f32x4){0.f, 0.f, 0.f, 0.f};
    ha[1] = (f32x4){0.f, 0.f, 0.f, 0.f};
    const bf16x8* wp = (const bf16x8*)(wf + WS_QW);
#pragma unroll
    for (int ks = 0; ks < 4; ++ks) {
      const bf16x8 hf = *(const bf16x8*)(P1 + (wave * 16 + lr) * SH + ks * 32 + lq * 8);
#pragma unroll
      for (int a = 0; a < 2; ++a)
        ha[a] = __builtin_amdgcn_mfma_f32_16x16x32_bf16(wp[(ks * 2 + a) * 64 + lane], hf, ha[a], 0, 0, 0);
    }
    float* op = out + ((size_t)b0 * NAG + wave * 16 + lr) * ADIM;
#pragma unroll
    for (int a = 0; a < 2; ++a) {
      const float4 bv4 = *(const float4*)(qb + a * 16 + lq * 4);
      float4 o;
      o.x = ha[a][0] + bv4.x; o.y = ha[a][1] + bv4.y;
      o.z = ha[a][2] + bv4.z; o.w = ha[a][3] + bv4.w;
      *(float4*)(op + a * 16 + lq * 4) = o;
    }
  }
}

extern "C" void kernel_launch(void* const* d_in, const int* in_sizes, int n_in,
                              void* d_out, int out_size, void* d_ws, size_t ws_size,
                              hipStream_t stream)
{
  const float* x     = (const float*)d_in[0];
  const float* mask  = (const float*)d_in[1];
  const float* enc_w = (const float*)d_in[2];
  const float* enc_b = (const float*)d_in[3];
  const float* a1_vw = (const float*)d_in[4];
  const float* a1_vb = (const float*)d_in[5];
  const float* a1_kw = (const float*)d_in[6];
  const float* a1_kb = (const float*)d_in[7];
  const float* a1_qw = (const float*)d_in[8];
  const float* a1_qb = (const float*)d_in[9];
  const float* a1_ow = (const float*)d_in[10];
  const float* a1_ob = (const float*)d_in[11];
  const float* a2_vw = (const float*)d_in[12];
  const float* a2_vb = (const float*)d_in[13];
  const float* a2_kw = (const float*)d_in[14];
  const float* a2_kb = (const float*)d_in[15];
  const float* a2_qw = (const float*)d_in[16];
  const float* a2_qb = (const float*)d_in[17];
  const float* a2_ow = (const float*)d_in[18];
  const float* a2_ob = (const float*)d_in[19];
  const float* q_w   = (const float*)d_in[20];
  const float* q_b   = (const float*)d_in[21];
  short* ws = (short*)d_ws;

  prep_weights<<<164, 256, 0, stream>>>(
      enc_w, a1_vw, a1_kw, a1_qw, a1_ow, a2_vw, a2_kw, a2_qw, a2_ow, q_w, ws);

  dgn_main<<<4096, 256, 0, stream>>>(
      x, mask, enc_b,
      a1_vb, a1_kb, a1_qb, a1_ob,
      a2_vb, a2_kb, a2_qb, a2_ob,
      q_b, ws, (float*)d_out);
}